// Round 14
// baseline (180.191 us; speedup 1.0000x reference)
//
#include <hip/hip_runtime.h>
#include <math.h>

#define Bn 32
#define Cn 64
#define Ln 2048
#define NFREQ 1025
#define S0c 341
#define S1c 341
#define S2c 343

#define PI_D 3.14159265358979323846

typedef double v4d __attribute__((ext_vector_type(4)));

// padded LDS index: breaks power-of-2 stride bank conflicts
#define PADIX(i) ((i) + ((i) >> 4))

// ---------------- K1: twiddle table tw[t] = e^{-2 pi i t / 2048}, t<2048 ----------------
__global__ void k_twiddle(double2* __restrict__ tw) {
    int t = blockIdx.x * blockDim.x + threadIdx.x;
    if (t < 2048) {
        double ang = -2.0 * PI_D * (double)t / 2048.0;
        double s, c;
        sincos(ang, &s, &c);
        tw[t] = make_double2(c, s);
    }
}

// radix-4 digit reversal of a 10-bit index
__device__ __forceinline__ int rev4_10(unsigned x) {
    unsigned t = __brev(x) >> 22;                       // full 10-bit reversal
    return (int)(((t & 0x155u) << 1) | ((t >> 1) & 0x155u));  // un-reverse bit pairs
}

// ---------------- K2: packed-real rfft, 2 rows/block, radix-4, stage-0 fused ----------------
__global__ __launch_bounds__(256) void k_fft(const float* __restrict__ X,
                                             const double2* __restrict__ tw,
                                             float* __restrict__ XF) {
    __shared__ double re[2][1088];
    __shared__ double im[2][1088];
    int row0 = blockIdx.x * 2;
    int tid = threadIdx.x;
    // ---- stage 0 (Q=256) in registers from global loads, both rows ----
    {
        int k = tid;
        double2 w1 = tw[2 * k];
        double2 w2 = tw[4 * k];
        double2 w3 = tw[6 * k];
        int i0 = PADIX(k), i1 = PADIX(k + 256), i2 = PADIX(k + 512), i3 = PADIX(k + 768);
        #pragma unroll
        for (int r = 0; r < 2; ++r) {
            const float2* xr = (const float2*)(X + (size_t)(row0 + r) * Ln);
            float2 v0 = xr[k];
            float2 v1 = xr[k + 256];
            float2 v2 = xr[k + 512];
            float2 v3 = xr[k + 768];
            double ar = (double)v0.x, ai = (double)v0.y;
            double br = (double)v1.x, bi = (double)v1.y;
            double cr = (double)v2.x, ci = (double)v2.y;
            double dr = (double)v3.x, di = (double)v3.y;
            double t0r = ar + cr, t0i = ai + ci;
            double t1r = ar - cr, t1i = ai - ci;
            double t2r = br + dr, t2i = bi + di;
            double t3r = br - dr, t3i = bi - di;
            re[r][i0] = t0r + t2r; im[r][i0] = t0i + t2i;
            double u1r = t1r + t3i, u1i = t1i - t3r;
            re[r][i1] = u1r * w1.x - u1i * w1.y; im[r][i1] = u1r * w1.y + u1i * w1.x;
            double u2r = t0r - t2r, u2i = t0i - t2i;
            re[r][i2] = u2r * w2.x - u2i * w2.y; im[r][i2] = u2r * w2.y + u2i * w2.x;
            double u3r = t1r - t3i, u3i = t1i + t3r;
            re[r][i3] = u3r * w3.x - u3i * w3.y; im[r][i3] = u3r * w3.y + u3i * w3.x;
        }
    }
    __syncthreads();
    // ---- stages 1..4 through LDS, twiddles shared across both rows ----
    #pragma unroll
    for (int s = 1; s < 5; ++s) {
        int log2Q = 8 - 2 * s;
        int Q = 1 << log2Q;
        int k = tid & (Q - 1);
        int g = tid >> log2Q;
        int base = (g << (log2Q + 2)) + k;
        int i0 = PADIX(base), i1 = PADIX(base + Q), i2 = PADIX(base + 2 * Q), i3 = PADIX(base + 3 * Q);
        int step = 2 << (2 * s);
        double2 w1 = tw[k * step];
        double2 w2 = tw[2 * k * step];
        double2 w3 = tw[3 * k * step];
        #pragma unroll
        for (int r = 0; r < 2; ++r) {
            double ar = re[r][i0], ai = im[r][i0];
            double br = re[r][i1], bi = im[r][i1];
            double cr = re[r][i2], ci = im[r][i2];
            double dr = re[r][i3], di = im[r][i3];
            double t0r = ar + cr, t0i = ai + ci;
            double t1r = ar - cr, t1i = ai - ci;
            double t2r = br + dr, t2i = bi + di;
            double t3r = br - dr, t3i = bi - di;
            re[r][i0] = t0r + t2r; im[r][i0] = t0i + t2i;
            double u1r = t1r + t3i, u1i = t1i - t3r;
            re[r][i1] = u1r * w1.x - u1i * w1.y; im[r][i1] = u1r * w1.y + u1i * w1.x;
            double u2r = t0r - t2r, u2i = t0i - t2i;
            re[r][i2] = u2r * w2.x - u2i * w2.y; im[r][i2] = u2r * w2.y + u2i * w2.x;
            double u3r = t1r - t3i, u3i = t1i + t3r;
            re[r][i3] = u3r * w3.x - u3i * w3.y; im[r][i3] = u3r * w3.y + u3i * w3.x;
        }
        __syncthreads();
    }
    // split: X[k] = E_k + e^{-2pi i k/2048} O_k (Z positions radix-4-digit-reversed)
    float* out0 = XF + (size_t)row0 * NFREQ;
    float* out1 = XF + (size_t)(row0 + 1) * NFREQ;
    for (int k = tid; k <= 1024; k += 256) {
        int rv = 0, rv2 = 0;
        double2 t = tw[0];
        if (k != 0 && k != 1024) {
            rv  = PADIX(rev4_10((unsigned)k));
            rv2 = PADIX(rev4_10((unsigned)(1024 - k)));
            t = tw[k];
        }
        #pragma unroll
        for (int r = 0; r < 2; ++r) {
            double Xr, Xi;
            if (k == 0)        { Xr = re[r][0] + im[r][0]; Xi = 0.0; }
            else if (k == 1024){ Xr = re[r][0] - im[r][0]; Xi = 0.0; }
            else {
                double Zr = re[r][rv],  Zi = im[r][rv];
                double Wr = re[r][rv2], Wi = im[r][rv2];
                double Er = 0.5 * (Zr + Wr), Ei = 0.5 * (Zi - Wi);
                double Or = 0.5 * (Zi + Wi), Oi = -0.5 * (Zr - Wr);
                Xr = Er + t.x * Or - t.y * Oi;
                Xi = Ei + t.x * Oi + t.y * Or;
            }
            float v = (float)sqrt(Xr * Xr + Xi * Xi);
            if (r == 0) out0[k] = v; else out1[k] = v;
        }
    }
}

// ---------------- K3: fused 3-band GEMM — BARRIER-FREE wave-private streaming ----------------
// grid (32, 6, 12) = 2304 blocks; block 256 = 4 waves. Each wave owns one 16x16 output
// tile and stages ITS OWN operand slices (16 X-rows, 16 A-cols) into a PRIVATE LDS
// region: zero inter-wave dependencies -> zero __syncthreads in the entire kernel.
// Each wave is an independent stream: global prefetch -> private LDS -> frags+MFMA,
// ordered by the wave's in-order DS pipe. Dual accumulator chains. BK=32.
__global__ __launch_bounds__(256) void k_gemm(const float* __restrict__ XF,
                                              const float* __restrict__ A0,
                                              const float* __restrict__ A1,
                                              const float* __restrict__ A2,
                                              double* __restrict__ Y) {
    const int Sarr[3] = {S0c, S1c, S2c};
    const int Oarr[3] = {0, S0c, S0c + S1c};
    int bz = blockIdx.z;
    int z = bz >> 2, q = bz & 3;
    const float* A = (z == 0) ? A0 : ((z == 1) ? A1 : A2);
    int S = Sarr[z], O = Oarr[z];
    int qm = q >> 1, qn = q & 1;

    __shared__ float sX[4][16][33];   // [wave][row][k] private slices
    __shared__ float sA[4][16][33];   // [wave][col][k]
    int tid = threadIdx.x;
    int lane = tid & 63, w = tid >> 6;
    int lm = (w >> 1) * 16, ln = (w & 1) * 16;    // wave's 16x16 tile in the 32x32 quadrant
    int r0 = blockIdx.x * 64 + qm * 32 + lm;      // wave's absolute row base
    int d0 = blockIdx.y * 64 + qn * 32 + ln;      // wave's absolute col base
    int fm = lane & 15, kq = lane >> 4;
    int kl = lane & 31, rl = lane >> 5;           // staging: k-local (coalesced), row base

    // ---- runtime layout calibration (proven round 7) ----
    v4d zero = {0.0, 0.0, 0.0, 0.0};
    double aval = (double)fm;
    v4d calR = __builtin_amdgcn_mfma_f64_16x16x4f64(aval, 1.0, zero, 0, 0, 0);
    v4d calC = __builtin_amdgcn_mfma_f64_16x16x4f64(1.0, aval, zero, 0, 0, 0);
    int rIdx[4], cIdx[4];
    #pragma unroll
    for (int i = 0; i < 4; ++i) {
        rIdx[i] = (int)(calR[i] * 0.25);
        cIdx[i] = (int)(calC[i] * 0.25);
    }

    auto load_tile = [&](int st, float* px, float* pa) {
        int ss = st * 32 + kl;
        bool sv = ss < S;
        #pragma unroll
        for (int i = 0; i < 8; ++i)
            px[i] = sv ? XF[(size_t)(r0 + rl + 2 * i) * NFREQ + O + ss] : 0.0f;
        #pragma unroll
        for (int j = 0; j < 8; ++j) {
            int d = d0 + rl + 2 * j;
            pa[j] = (sv && d < S) ? A[(size_t)d * S + ss] : 0.0f;
        }
    };

    v4d accE = zero, accO = zero;   // two independent chains
    float px[8], pa[8];
    load_tile(0, px, pa);
    int nsteps = (S + 31) / 32;   // 11
    for (int st = 0; st < nsteps; ++st) {
        // write this step's operands into the wave's private LDS region
        #pragma unroll
        for (int i = 0; i < 8; ++i) sX[w][rl + 2 * i][kl] = px[i];
        #pragma unroll
        for (int j = 0; j < 8; ++j) sA[w][rl + 2 * j][kl] = pa[j];
        // prefetch next step from global while MFMAs run
        if (st + 1 < nsteps) load_tile(st + 1, px, pa);
        // frags + MFMAs (wave-private LDS; in-order DS pipe guarantees RAW)
        #pragma unroll
        for (int t = 0; t < 4; ++t) {
            int kE = 8 * t + kq;
            int kO = 8 * t + 4 + kq;
            double aE = (double)sX[w][fm][kE];
            double bE = (double)sA[w][fm][kE];
            double aO = (double)sX[w][fm][kO];
            double bO = (double)sA[w][fm][kO];
            accE = __builtin_amdgcn_mfma_f64_16x16x4f64(aE, bE, accE, 0, 0, 0);
            accO = __builtin_amdgcn_mfma_f64_16x16x4f64(aO, bO, accO, 0, 0, 0);
        }
    }
    v4d acc = accE + accO;
    #pragma unroll
    for (int i = 0; i < 4; ++i) {
        int row = r0 + rIdx[i];
        int d = d0 + cIdx[i];
        if (d < S) Y[(size_t)row * NFREQ + O + d] = acc[i];
    }
}

// ---------------- K4: weighted Gram partials via f64 MFMA, G = Yw Yw^T (round-8 form) ----------------
// grid (32 batches, 8 dim-chunks); block 256 = 4 waves (2x2 quadrants of the 64x64 G).
__global__ __launch_bounds__(256) void k_dist(const double* __restrict__ Y,
                                              const float* __restrict__ fw,
                                              double* __restrict__ part) {
    __shared__ double sY[64][34];   // [row][k] f64
    int b = blockIdx.x;
    int chunk = blockIdx.y;
    int dlo = chunk * 128;
    int dhi = (chunk == 7) ? NFREQ : dlo + 128;
    int tid = threadIdx.x;
    int lane = tid & 63, w = tid >> 6;
    int wm = (w >> 1) * 32, wn = (w & 1) * 32;
    int fm = lane & 15, kq = lane >> 4;
    int kl = tid & 31, rl = tid >> 5;

    double f0 = (double)fw[0], f1 = (double)fw[1], f2 = (double)fw[2];
    double m = fmax(f0, fmax(f1, f2));
    double e0 = exp(f0 - m), e1 = exp(f1 - m), e2 = exp(f2 - m);
    double esum = e0 + e1 + e2;
    double sw0 = sqrt(e0 / esum), sw1 = sqrt(e1 / esum), sw2 = sqrt(e2 / esum);

    v4d zero = {0.0, 0.0, 0.0, 0.0};
    double aval = (double)fm;
    v4d calR = __builtin_amdgcn_mfma_f64_16x16x4f64(aval, 1.0, zero, 0, 0, 0);
    v4d calC = __builtin_amdgcn_mfma_f64_16x16x4f64(1.0, aval, zero, 0, 0, 0);
    int rIdx[4], cIdx[4];
    #pragma unroll
    for (int i = 0; i < 4; ++i) {
        rIdx[i] = (int)(calR[i] * 0.25);
        cIdx[i] = (int)(calC[i] * 0.25);
    }

    const double* Yb = Y + (size_t)b * Cn * NFREQ;
    auto load_tile = [&](int k0, double* py) {
        int d = dlo + k0 + kl;
        bool dv = d < dhi;
        double sw = dv ? ((d < S0c) ? sw0 : ((d < S0c + S1c) ? sw1 : sw2)) : 0.0;
        #pragma unroll
        for (int i = 0; i < 8; ++i)
            py[i] = dv ? Yb[(size_t)(rl + 8 * i) * NFREQ + d] * sw : 0.0;
    };

    v4d acc00 = zero, acc01 = zero, acc10 = zero, acc11 = zero;
    double py[8];
    load_tile(0, py);
    int nsteps = (dhi - dlo + 31) / 32;
    for (int st = 0; st < nsteps; ++st) {
        __syncthreads();
        #pragma unroll
        for (int i = 0; i < 8; ++i) sY[rl + 8 * i][kl] = py[i];
        __syncthreads();
        if (st + 1 < nsteps) load_tile((st + 1) * 32, py);
        #pragma unroll
        for (int t = 0; t < 8; ++t) {
            int k = 4 * t + kq;
            double a0 = sY[wm + fm][k];
            double a1 = sY[wm + 16 + fm][k];
            double b0 = sY[wn + fm][k];
            double b1 = sY[wn + 16 + fm][k];
            acc00 = __builtin_amdgcn_mfma_f64_16x16x4f64(a0, b0, acc00, 0, 0, 0);
            acc01 = __builtin_amdgcn_mfma_f64_16x16x4f64(a0, b1, acc01, 0, 0, 0);
            acc10 = __builtin_amdgcn_mfma_f64_16x16x4f64(a1, b0, acc10, 0, 0, 0);
            acc11 = __builtin_amdgcn_mfma_f64_16x16x4f64(a1, b1, acc11, 0, 0, 0);
        }
    }
    double* pb = part + (((size_t)b * 8 + chunk) << 12);
    #pragma unroll
    for (int i = 0; i < 4; ++i) {
        int rowA = wm + rIdx[i], rowB = rowA + 16;
        int cA = wn + cIdx[i], cB = cA + 16;
        pb[rowA * 64 + cA] = acc00[i];
        pb[rowA * 64 + cB] = acc01[i];
        pb[rowB * 64 + cA] = acc10[i];
        pb[rowB * 64 + cB] = acc11[i];
    }
}

// ---------------- K5: sum Gram partials, dist = Gii+Gjj-2Gij, gumbel decision ----------------
// grid (32 batches, 16 row-groups); block 256 = 4 waves, one wave per matrix row.
__global__ __launch_bounds__(256) void k_decide(const double* __restrict__ part,
                                                const float* __restrict__ gum,
                                                float* __restrict__ out) {
    __shared__ double sQ[64];
    int b = blockIdx.x;
    int tid = threadIdx.x;
    const double* pb = part + (((size_t)b * 8) << 12);
    if (tid < 64) {
        double q = 0.0;
        #pragma unroll
        for (int c = 0; c < 8; ++c) q += pb[((size_t)c << 12) + tid * 65];
        sQ[tid] = q;
    }
    __syncthreads();
    int i = blockIdx.y * 4 + (tid >> 6);
    int j = tid & 63;
    double g = 0.0;
    #pragma unroll
    for (int c = 0; c < 8; ++c) g += pb[((size_t)c << 12) + i * 64 + j];
    double dist = fmax(sQ[i] + sQ[j] - 2.0 * g, 0.0);
    double e = (i == j) ? 0.0 : 1.0 / (dist + 1e-10);
    double emax = e;
    #pragma unroll
    for (int off = 32; off; off >>= 1)
        emax = fmax(emax, __shfl_xor(emax, off, 64));
    double p = (i == j) ? 0.99 : (e / emax) * 0.99;
    double l0 = log(p / (1.0 - p));
    double l1 = log((1.0 - p) / p);
    int idx = i * 64 + j;
    const float* gb = gum + (size_t)b * 8192;
    double y0 = l0 + (double)gb[2 * idx];
    double y1 = l1 + (double)gb[2 * idx + 1];
    out[(size_t)b * 4096 + idx] = (y0 >= y1) ? 1.0f : 0.0f;  // ST == one-hot exactly
}

// ---------------- launcher ----------------
extern "C" void kernel_launch(void* const* d_in, const int* in_sizes, int n_in,
                              void* d_out, int out_size, void* d_ws, size_t ws_size,
                              hipStream_t stream) {
    const float* X  = (const float*)d_in[0];
    const float* A0 = (const float*)d_in[1];
    const float* A1 = (const float*)d_in[2];
    const float* A2 = (const float*)d_in[3];
    const float* fw = (const float*)d_in[4];
    const float* gm = (const float*)d_in[5];
    float* out = (float*)d_out;

    char* ws = (char*)d_ws;
    double2* tw  = (double2*)(ws);                 // 2048*16 = 32,768 B
    float*   XF  = (float*)(ws + 32768);           // 8,396,800 B
    double*  Y   = (double*)(ws + 8429568);        // 16,793,600 B (ends 25,223,168)
    // part aliases XF (dead after gemm): 32*8*4096*8 = 8,388,608 B
    double*  part = (double*)(ws + 32768);

    k_twiddle<<<8, 256, 0, stream>>>(tw);
    k_fft<<<Bn * Cn / 2, 256, 0, stream>>>(X, tw, XF);
    k_gemm<<<dim3(32, 6, 12), 256, 0, stream>>>(XF, A0, A1, A2, Y);
    k_dist<<<dim3(Bn, 8), 256, 0, stream>>>(Y, fw, part);
    k_decide<<<dim3(Bn, 16), 256, 0, stream>>>(part, gm, out);
}

// Round 15
// 161.723 us; speedup vs baseline: 1.1142x; 1.1142x over previous
//
#include <hip/hip_runtime.h>
#include <math.h>

#define Bn 32
#define Cn 64
#define Ln 2048
#define NFREQ 1025
#define S0c 341
#define S1c 341
#define S2c 343

#define PI_D 3.14159265358979323846

typedef double v4d __attribute__((ext_vector_type(4)));

// padded LDS index: breaks power-of-2 stride bank conflicts
#define PADIX(i) ((i) + ((i) >> 4))

// ---------------- K1: twiddle table tw[t] = e^{-2 pi i t / 2048}, t<2048 ----------------
__global__ void k_twiddle(double2* __restrict__ tw) {
    int t = blockIdx.x * blockDim.x + threadIdx.x;
    if (t < 2048) {
        double ang = -2.0 * PI_D * (double)t / 2048.0;
        double s, c;
        sincos(ang, &s, &c);
        tw[t] = make_double2(c, s);
    }
}

// radix-4 digit reversal of a 10-bit index
__device__ __forceinline__ int rev4_10(unsigned x) {
    unsigned t = __brev(x) >> 22;                       // full 10-bit reversal
    return (int)(((t & 0x155u) << 1) | ((t >> 1) & 0x155u));  // un-reverse bit pairs
}

// ---------------- K2: packed-real rfft, 2 rows/block, radix-4, stage-0 fused ----------------
__global__ __launch_bounds__(256) void k_fft(const float* __restrict__ X,
                                             const double2* __restrict__ tw,
                                             float* __restrict__ XF) {
    __shared__ double re[2][1088];
    __shared__ double im[2][1088];
    int row0 = blockIdx.x * 2;
    int tid = threadIdx.x;
    // ---- stage 0 (Q=256) in registers from global loads, both rows ----
    {
        int k = tid;
        double2 w1 = tw[2 * k];
        double2 w2 = tw[4 * k];
        double2 w3 = tw[6 * k];
        int i0 = PADIX(k), i1 = PADIX(k + 256), i2 = PADIX(k + 512), i3 = PADIX(k + 768);
        #pragma unroll
        for (int r = 0; r < 2; ++r) {
            const float2* xr = (const float2*)(X + (size_t)(row0 + r) * Ln);
            float2 v0 = xr[k];
            float2 v1 = xr[k + 256];
            float2 v2 = xr[k + 512];
            float2 v3 = xr[k + 768];
            double ar = (double)v0.x, ai = (double)v0.y;
            double br = (double)v1.x, bi = (double)v1.y;
            double cr = (double)v2.x, ci = (double)v2.y;
            double dr = (double)v3.x, di = (double)v3.y;
            double t0r = ar + cr, t0i = ai + ci;
            double t1r = ar - cr, t1i = ai - ci;
            double t2r = br + dr, t2i = bi + di;
            double t3r = br - dr, t3i = bi - di;
            re[r][i0] = t0r + t2r; im[r][i0] = t0i + t2i;
            double u1r = t1r + t3i, u1i = t1i - t3r;
            re[r][i1] = u1r * w1.x - u1i * w1.y; im[r][i1] = u1r * w1.y + u1i * w1.x;
            double u2r = t0r - t2r, u2i = t0i - t2i;
            re[r][i2] = u2r * w2.x - u2i * w2.y; im[r][i2] = u2r * w2.y + u2i * w2.x;
            double u3r = t1r - t3i, u3i = t1i + t3r;
            re[r][i3] = u3r * w3.x - u3i * w3.y; im[r][i3] = u3r * w3.y + u3i * w3.x;
        }
    }
    __syncthreads();
    // ---- stages 1..4 through LDS, twiddles shared across both rows ----
    #pragma unroll
    for (int s = 1; s < 5; ++s) {
        int log2Q = 8 - 2 * s;
        int Q = 1 << log2Q;
        int k = tid & (Q - 1);
        int g = tid >> log2Q;
        int base = (g << (log2Q + 2)) + k;
        int i0 = PADIX(base), i1 = PADIX(base + Q), i2 = PADIX(base + 2 * Q), i3 = PADIX(base + 3 * Q);
        int step = 2 << (2 * s);
        double2 w1 = tw[k * step];
        double2 w2 = tw[2 * k * step];
        double2 w3 = tw[3 * k * step];
        #pragma unroll
        for (int r = 0; r < 2; ++r) {
            double ar = re[r][i0], ai = im[r][i0];
            double br = re[r][i1], bi = im[r][i1];
            double cr = re[r][i2], ci = im[r][i2];
            double dr = re[r][i3], di = im[r][i3];
            double t0r = ar + cr, t0i = ai + ci;
            double t1r = ar - cr, t1i = ai - ci;
            double t2r = br + dr, t2i = bi + di;
            double t3r = br - dr, t3i = bi - di;
            re[r][i0] = t0r + t2r; im[r][i0] = t0i + t2i;
            double u1r = t1r + t3i, u1i = t1i - t3r;
            re[r][i1] = u1r * w1.x - u1i * w1.y; im[r][i1] = u1r * w1.y + u1i * w1.x;
            double u2r = t0r - t2r, u2i = t0i - t2i;
            re[r][i2] = u2r * w2.x - u2i * w2.y; im[r][i2] = u2r * w2.y + u2i * w2.x;
            double u3r = t1r - t3i, u3i = t1i + t3r;
            re[r][i3] = u3r * w3.x - u3i * w3.y; im[r][i3] = u3r * w3.y + u3i * w3.x;
        }
        __syncthreads();
    }
    // split: X[k] = E_k + e^{-2pi i k/2048} O_k (Z positions radix-4-digit-reversed)
    float* out0 = XF + (size_t)row0 * NFREQ;
    float* out1 = XF + (size_t)(row0 + 1) * NFREQ;
    for (int k = tid; k <= 1024; k += 256) {
        int rv = 0, rv2 = 0;
        double2 t = tw[0];
        if (k != 0 && k != 1024) {
            rv  = PADIX(rev4_10((unsigned)k));
            rv2 = PADIX(rev4_10((unsigned)(1024 - k)));
            t = tw[k];
        }
        #pragma unroll
        for (int r = 0; r < 2; ++r) {
            double Xr, Xi;
            if (k == 0)        { Xr = re[r][0] + im[r][0]; Xi = 0.0; }
            else if (k == 1024){ Xr = re[r][0] - im[r][0]; Xi = 0.0; }
            else {
                double Zr = re[r][rv],  Zi = im[r][rv];
                double Wr = re[r][rv2], Wi = im[r][rv2];
                double Er = 0.5 * (Zr + Wr), Ei = 0.5 * (Zi - Wi);
                double Or = 0.5 * (Zi + Wi), Oi = -0.5 * (Zr - Wr);
                Xr = Er + t.x * Or - t.y * Oi;
                Xi = Ei + t.x * Oi + t.y * Or;
            }
            float v = (float)sqrt(Xr * Xr + Xi * Xi);
            if (r == 0) out0[k] = v; else out1[k] = v;
        }
    }
}

// ---------------- K3: fused 3-band GEMM, quadrant-split, v_mfma_f64_16x16x4 ----------------
// Round-11 configuration exactly (best measured: 50.2 us, conflicts 0).
// grid (32 row-tiles, 6 col-tiles, 3 bands x 4 quadrants) = 2304 blocks (~9/CU);
// block 256 = 4 waves, each wave one 16x16 output tile, single accumulator chain, BK=32.
__global__ __launch_bounds__(256) void k_gemm(const float* __restrict__ XF,
                                              const float* __restrict__ A0,
                                              const float* __restrict__ A1,
                                              const float* __restrict__ A2,
                                              double* __restrict__ Y) {
    const int Sarr[3] = {S0c, S1c, S2c};
    const int Oarr[3] = {0, S0c, S0c + S1c};
    int bz = blockIdx.z;
    int z = bz >> 2, q = bz & 3;
    const float* A = (z == 0) ? A0 : ((z == 1) ? A1 : A2);
    int S = Sarr[z], O = Oarr[z];
    int qm = q >> 1, qn = q & 1;

    __shared__ float sX[32][34];   // [row][k] (conflict-free, proven rounds 8/11)
    __shared__ float sA[32][34];   // [col(d)][k]
    int r0 = blockIdx.x * 64 + qm * 32;
    int d0 = blockIdx.y * 64 + qn * 32;
    int tid = threadIdx.x;
    int lane = tid & 63, w = tid >> 6;
    int lm = (w >> 1) * 16, ln = (w & 1) * 16;   // wave's 16x16 tile within the 32x32
    int fm = lane & 15, kq = lane >> 4;
    int kl = tid & 31, rl = tid >> 5;            // staging coords (rl 0..7)

    // ---- runtime layout calibration (proven round 7) ----
    v4d zero = {0.0, 0.0, 0.0, 0.0};
    double aval = (double)fm;
    v4d calR = __builtin_amdgcn_mfma_f64_16x16x4f64(aval, 1.0, zero, 0, 0, 0);
    v4d calC = __builtin_amdgcn_mfma_f64_16x16x4f64(1.0, aval, zero, 0, 0, 0);
    int rIdx[4], cIdx[4];
    #pragma unroll
    for (int i = 0; i < 4; ++i) {
        rIdx[i] = (int)(calR[i] * 0.25);
        cIdx[i] = (int)(calC[i] * 0.25);
    }

    auto load_tile = [&](int st, float* px, float* pa) {
        int ss = st * 32 + kl;
        bool sv = ss < S;
        #pragma unroll
        for (int i = 0; i < 4; ++i)
            px[i] = sv ? XF[(size_t)(r0 + rl + 8 * i) * NFREQ + O + ss] : 0.0f;
        #pragma unroll
        for (int j = 0; j < 4; ++j) {
            int d = d0 + rl + 8 * j;
            pa[j] = (sv && d < S) ? A[(size_t)d * S + ss] : 0.0f;
        }
    };

    v4d acc = zero;
    float px[4], pa[4];
    load_tile(0, px, pa);
    int nsteps = (S + 31) / 32;   // 11
    for (int st = 0; st < nsteps; ++st) {
        __syncthreads();
        #pragma unroll
        for (int i = 0; i < 4; ++i) sX[rl + 8 * i][kl] = px[i];
        #pragma unroll
        for (int j = 0; j < 4; ++j) sA[rl + 8 * j][kl] = pa[j];
        __syncthreads();
        if (st + 1 < nsteps) load_tile(st + 1, px, pa);
        #pragma unroll
        for (int t = 0; t < 8; ++t) {
            int k = 4 * t + kq;
            double a = (double)sX[lm + fm][k];
            double b = (double)sA[ln + fm][k];
            acc = __builtin_amdgcn_mfma_f64_16x16x4f64(a, b, acc, 0, 0, 0);
        }
    }
    #pragma unroll
    for (int i = 0; i < 4; ++i) {
        int row = r0 + lm + rIdx[i];
        int d = d0 + ln + cIdx[i];
        if (d < S) Y[(size_t)row * NFREQ + O + d] = acc[i];
    }
}

// ---------------- K4: weighted Gram partials via f64 MFMA, G = Yw Yw^T (round-8 form) ----------------
// grid (32 batches, 8 dim-chunks); block 256 = 4 waves (2x2 quadrants of the 64x64 G).
__global__ __launch_bounds__(256) void k_dist(const double* __restrict__ Y,
                                              const float* __restrict__ fw,
                                              double* __restrict__ part) {
    __shared__ double sY[64][34];   // [row][k] f64
    int b = blockIdx.x;
    int chunk = blockIdx.y;
    int dlo = chunk * 128;
    int dhi = (chunk == 7) ? NFREQ : dlo + 128;
    int tid = threadIdx.x;
    int lane = tid & 63, w = tid >> 6;
    int wm = (w >> 1) * 32, wn = (w & 1) * 32;
    int fm = lane & 15, kq = lane >> 4;
    int kl = tid & 31, rl = tid >> 5;

    double f0 = (double)fw[0], f1 = (double)fw[1], f2 = (double)fw[2];
    double m = fmax(f0, fmax(f1, f2));
    double e0 = exp(f0 - m), e1 = exp(f1 - m), e2 = exp(f2 - m);
    double esum = e0 + e1 + e2;
    double sw0 = sqrt(e0 / esum), sw1 = sqrt(e1 / esum), sw2 = sqrt(e2 / esum);

    v4d zero = {0.0, 0.0, 0.0, 0.0};
    double aval = (double)fm;
    v4d calR = __builtin_amdgcn_mfma_f64_16x16x4f64(aval, 1.0, zero, 0, 0, 0);
    v4d calC = __builtin_amdgcn_mfma_f64_16x16x4f64(1.0, aval, zero, 0, 0, 0);
    int rIdx[4], cIdx[4];
    #pragma unroll
    for (int i = 0; i < 4; ++i) {
        rIdx[i] = (int)(calR[i] * 0.25);
        cIdx[i] = (int)(calC[i] * 0.25);
    }

    const double* Yb = Y + (size_t)b * Cn * NFREQ;
    auto load_tile = [&](int k0, double* py) {
        int d = dlo + k0 + kl;
        bool dv = d < dhi;
        double sw = dv ? ((d < S0c) ? sw0 : ((d < S0c + S1c) ? sw1 : sw2)) : 0.0;
        #pragma unroll
        for (int i = 0; i < 8; ++i)
            py[i] = dv ? Yb[(size_t)(rl + 8 * i) * NFREQ + d] * sw : 0.0;
    };

    v4d acc00 = zero, acc01 = zero, acc10 = zero, acc11 = zero;
    double py[8];
    load_tile(0, py);
    int nsteps = (dhi - dlo + 31) / 32;
    for (int st = 0; st < nsteps; ++st) {
        __syncthreads();
        #pragma unroll
        for (int i = 0; i < 8; ++i) sY[rl + 8 * i][kl] = py[i];
        __syncthreads();
        if (st + 1 < nsteps) load_tile((st + 1) * 32, py);
        #pragma unroll
        for (int t = 0; t < 8; ++t) {
            int k = 4 * t + kq;
            double a0 = sY[wm + fm][k];
            double a1 = sY[wm + 16 + fm][k];
            double b0 = sY[wn + fm][k];
            double b1 = sY[wn + 16 + fm][k];
            acc00 = __builtin_amdgcn_mfma_f64_16x16x4f64(a0, b0, acc00, 0, 0, 0);
            acc01 = __builtin_amdgcn_mfma_f64_16x16x4f64(a0, b1, acc01, 0, 0, 0);
            acc10 = __builtin_amdgcn_mfma_f64_16x16x4f64(a1, b0, acc10, 0, 0, 0);
            acc11 = __builtin_amdgcn_mfma_f64_16x16x4f64(a1, b1, acc11, 0, 0, 0);
        }
    }
    double* pb = part + (((size_t)b * 8 + chunk) << 12);
    #pragma unroll
    for (int i = 0; i < 4; ++i) {
        int rowA = wm + rIdx[i], rowB = rowA + 16;
        int cA = wn + cIdx[i], cB = cA + 16;
        pb[rowA * 64 + cA] = acc00[i];
        pb[rowA * 64 + cB] = acc01[i];
        pb[rowB * 64 + cA] = acc10[i];
        pb[rowB * 64 + cB] = acc11[i];
    }
}

// ---------------- K5: sum Gram partials, dist = Gii+Gjj-2Gij, gumbel decision ----------------
// grid (32 batches, 16 row-groups); block 256 = 4 waves, one wave per matrix row.
__global__ __launch_bounds__(256) void k_decide(const double* __restrict__ part,
                                                const float* __restrict__ gum,
                                                float* __restrict__ out) {
    __shared__ double sQ[64];
    int b = blockIdx.x;
    int tid = threadIdx.x;
    const double* pb = part + (((size_t)b * 8) << 12);
    if (tid < 64) {
        double q = 0.0;
        #pragma unroll
        for (int c = 0; c < 8; ++c) q += pb[((size_t)c << 12) + tid * 65];
        sQ[tid] = q;
    }
    __syncthreads();
    int i = blockIdx.y * 4 + (tid >> 6);
    int j = tid & 63;
    double g = 0.0;
    #pragma unroll
    for (int c = 0; c < 8; ++c) g += pb[((size_t)c << 12) + i * 64 + j];
    double dist = fmax(sQ[i] + sQ[j] - 2.0 * g, 0.0);
    double e = (i == j) ? 0.0 : 1.0 / (dist + 1e-10);
    double emax = e;
    #pragma unroll
    for (int off = 32; off; off >>= 1)
        emax = fmax(emax, __shfl_xor(emax, off, 64));
    double p = (i == j) ? 0.99 : (e / emax) * 0.99;
    double l0 = log(p / (1.0 - p));
    double l1 = log((1.0 - p) / p);
    int idx = i * 64 + j;
    const float* gb = gum + (size_t)b * 8192;
    double y0 = l0 + (double)gb[2 * idx];
    double y1 = l1 + (double)gb[2 * idx + 1];
    out[(size_t)b * 4096 + idx] = (y0 >= y1) ? 1.0f : 0.0f;  // ST == one-hot exactly
}

// ---------------- launcher ----------------
extern "C" void kernel_launch(void* const* d_in, const int* in_sizes, int n_in,
                              void* d_out, int out_size, void* d_ws, size_t ws_size,
                              hipStream_t stream) {
    const float* X  = (const float*)d_in[0];
    const float* A0 = (const float*)d_in[1];
    const float* A1 = (const float*)d_in[2];
    const float* A2 = (const float*)d_in[3];
    const float* fw = (const float*)d_in[4];
    const float* gm = (const float*)d_in[5];
    float* out = (float*)d_out;

    char* ws = (char*)d_ws;
    double2* tw  = (double2*)(ws);                 // 2048*16 = 32,768 B
    float*   XF  = (float*)(ws + 32768);           // 8,396,800 B
    double*  Y   = (double*)(ws + 8429568);        // 16,793,600 B (ends 25,223,168)
    // part aliases XF (dead after gemm): 32*8*4096*8 = 8,388,608 B
    double*  part = (double*)(ws + 32768);

    k_twiddle<<<8, 256, 0, stream>>>(tw);
    k_fft<<<Bn * Cn / 2, 256, 0, stream>>>(X, tw, XF);
    k_gemm<<<dim3(32, 6, 12), 256, 0, stream>>>(XF, A0, A1, A2, Y);
    k_dist<<<dim3(Bn, 8), 256, 0, stream>>>(Y, fw, part);
    k_decide<<<dim3(Bn, 16), 256, 0, stream>>>(part, gm, out);
}